// Round 15
// baseline (152.359 us; speedup 1.0000x reference)
//
#include <hip/hip_runtime.h>
#include <math.h>

#define TT 2048
#define LK 769
#define NF 20
#define NS 128
#define NB 18

typedef __attribute__((ext_vector_type(8))) short short8;
typedef __attribute__((ext_vector_type(4))) float f32x4;

// ---------------------------------------------------------------------------
// Kernel T: build the twiddle table in global memory (read-only thereafter;
// L1-cached in convhil). tw[half+j] = exp(-i*pi*j/half), same formula as the
// old LDS init -> bit-identical values.
// ---------------------------------------------------------------------------
__global__ void tw_kernel(float2* __restrict__ tw) {
  int i = blockIdx.x * 256 + threadIdx.x;
  if (i >= TT) return;
  if (i == 0) { tw[0] = make_float2(1.f, 0.f); return; }
  int half = 1 << (31 - __clz(i));
  int j = i - half;
  float ang = -3.14159265358979323846f * (float)j / (float)half;
  float s, c;
  sincosf(ang, &s, &c);
  tw[i] = make_float2(c, s);
}

// ---------------------------------------------------------------------------
// Kernel A: FUSED conv + Hilbert (R14 structure). R15: twiddles from global
// (L1-resident) instead of LDS -> LDS 34.3KB -> ~17.7KB -> 8 blocks/CU
// (was 4), doubling barrier-latency hiding for the 12 FFT stages.
// ---------------------------------------------------------------------------
__global__ __launch_bounds__(256) void convhil_kernel(const float* __restrict__ x,
                                                      const float* __restrict__ ker,
                                                      const float2* __restrict__ tw,
                                                      float* __restrict__ filt) {
  __shared__ __align__(16) float smem[4400];   // w[2832]+hs1[784]+hs2[784]; z overlays
  __shared__ int red[4][4];
  float* w   = smem;
  float* hs1 = smem + 2832;
  float* hs2 = smem + 3616;
  float2* z  = (float2*)smem;                  // 2048 float2 = 4096 floats < 4400
  const int tid = threadIdx.x;
  const int ord = blockIdx.x;
  const int p = ord / NS;                   // 0..9, longest pair first
  const int n = ord % NS;
  const int o1 = p;                          // pha band
  const int o2 = 10 + (9 - p);               // amp band (short with long)
  const float* xr = x + n * TT;
  for (int j = tid; j < 2832; j += 256) {
    float v = 0.f;
    if (j < 2816) {
      int m = j - 384;              // spad[j+384] -> original index (j+384)-768
      if (m < 0) m = -m;            // reflect (edge excluded)
      if (m > 2047) m = 4094 - m;
      v = xr[m];
    }
    w[j] = v;
  }
  const float* kr1 = ker + o1 * LK;
  const float* kr2 = ker + o2 * LK;
  int k0 = 784, k1 = 0, m0 = 784, m1 = 0;
  for (int k = tid; k < 784; k += 256) {
    float v1 = 0.f, v2 = 0.f;
    if (k < LK) {
      v1 = 0.5f * (kr1[k] + kr1[LK - 1 - k]);
      v2 = 0.5f * (kr2[k] + kr2[LK - 1 - k]);
    }
    hs1[k] = v1;
    hs2[k] = v2;
    if (v1 != 0.f) { k0 = min(k0, k); k1 = max(k1, k + 1); }
    if (v2 != 0.f) { m0 = min(m0, k); m1 = max(m1, k + 1); }
  }
#pragma unroll
  for (int off = 32; off > 0; off >>= 1) {
    k0 = min(k0, __shfl_down(k0, off));
    k1 = max(k1, __shfl_down(k1, off));
    m0 = min(m0, __shfl_down(m0, off));
    m1 = max(m1, __shfl_down(m1, off));
  }
  const int wid = tid >> 6;
  if ((tid & 63) == 0) { red[wid][0] = k0; red[wid][1] = k1; red[wid][2] = m0; red[wid][3] = m1; }
  __syncthreads();
  k0 = min(min(red[0][0], red[1][0]), min(red[2][0], red[3][0]));
  k1 = max(max(red[0][1], red[1][1]), max(red[2][1], red[3][1]));
  m0 = min(min(red[0][2], red[1][2]), min(red[2][2], red[3][2]));
  m1 = max(max(red[0][3], red[1][3]), max(red[2][3], red[3][3]));
  // 8-aligned ranges (extra taps are exact zeros -> bit-exact)
  const int A0 = __builtin_amdgcn_readfirstlane(k0 & ~7);
  const int A1 = __builtin_amdgcn_readfirstlane((k1 + 7) & ~7);
  const int B0 = __builtin_amdgcn_readfirstlane(m0 & ~7);
  const int B1 = __builtin_amdgcn_readfirstlane((m1 + 7) & ~7);
  const int U0 = min(A0, B0);
  const int U1 = max(A1, B1);

  const int bA = 4 * tid;           // group A outputs [bA, bA+4)
  const int bB = 1024 + 4 * tid;    // group B outputs [bB, bB+4)
  float acc1A[4], acc1B[4], acc2A[4], acc2B[4];
#pragma unroll
  for (int r = 0; r < 4; ++r) { acc1A[r] = 0.f; acc1B[r] = 0.f; acc2A[r] = 0.f; acc2B[r] = 0.f; }
  if (U0 < U1) {
    // rolling window: a0..a2 cover w[bA+k .. bA+k+12)
    float4 a0 = *(const float4*)&w[bA + U0];
    float4 a1 = *(const float4*)&w[bA + U0 + 4];
    float4 a2 = *(const float4*)&w[bA + U0 + 8];
    float4 b0 = *(const float4*)&w[bB + U0];
    float4 b1 = *(const float4*)&w[bB + U0 + 4];
    float4 b2 = *(const float4*)&w[bB + U0 + 8];
    float4 h1a = *(const float4*)&hs1[U0];
    float4 h1b = *(const float4*)&hs1[U0 + 4];
    float4 h2a = *(const float4*)&hs2[U0];
    float4 h2b = *(const float4*)&hs2[U0 + 4];
    for (int k = U0; k < U1; k += 8) {
      float4 a3 = *(const float4*)&w[bA + k + 12];
      float4 a4 = *(const float4*)&w[bA + k + 16];
      float4 b3 = *(const float4*)&w[bB + k + 12];
      float4 b4 = *(const float4*)&w[bB + k + 16];
      float4 h1an = *(const float4*)&hs1[k + 8];
      float4 h1bn = *(const float4*)&hs1[k + 12];
      float4 h2an = *(const float4*)&hs2[k + 8];
      float4 h2bn = *(const float4*)&hs2[k + 12];
      float wa[11] = {a0.x, a0.y, a0.z, a0.w, a1.x, a1.y, a1.z, a1.w,
                      a2.x, a2.y, a2.z};
      float wb[11] = {b0.x, b0.y, b0.z, b0.w, b1.x, b1.y, b1.z, b1.w,
                      b2.x, b2.y, b2.z};
      float h1[8] = {h1a.x, h1a.y, h1a.z, h1a.w, h1b.x, h1b.y, h1b.z, h1b.w};
      float h2[8] = {h2a.x, h2a.y, h2a.z, h2a.w, h2b.x, h2b.y, h2b.z, h2b.w};
      if (k >= A0 && k < A1) {
#pragma unroll
        for (int r = 0; r < 4; ++r) {
#pragma unroll
          for (int j = 0; j < 8; ++j) {
            acc1A[r] = fmaf(h1[j], wa[r + j], acc1A[r]);
            acc1B[r] = fmaf(h1[j], wb[r + j], acc1B[r]);
          }
        }
      }
      if (k >= B0 && k < B1) {
#pragma unroll
        for (int r = 0; r < 4; ++r) {
#pragma unroll
          for (int j = 0; j < 8; ++j) {
            acc2A[r] = fmaf(h2[j], wa[r + j], acc2A[r]);
            acc2B[r] = fmaf(h2[j], wb[r + j], acc2B[r]);
          }
        }
      }
      a0 = a2; a1 = a3; a2 = a4;
      b0 = b2; b1 = b3; b2 = b4;
      h1a = h1an; h1b = h1bn;
      h2a = h2an; h2b = h2bn;
    }
  }
  // ---- hand off to FFT: z = out1 + i*out2 (overlays dead w/hs region) ----
  __syncthreads();                    // everyone done reading w/hs
#pragma unroll
  for (int r = 0; r < 4; ++r) {
    z[bA + r] = make_float2(acc1A[r], acc2A[r]);
    z[bB + r] = make_float2(acc1B[r], acc2B[r]);
  }
  __syncthreads();
  // ---- forward radix-2 DIF stage (half=1024) ----
  for (int bf = tid; bf < 1024; bf += 256) {
    const float2 t = tw[1024 + bf];
    const float2 u = z[bf];
    const float2 v = z[bf + 1024];
    z[bf] = make_float2(u.x + v.x, u.y + v.y);
    const float dr = u.x - v.x, di = u.y - v.y;
    z[bf + 1024] = make_float2(fmaf(t.x, dr, -(t.y * di)),
                               fmaf(t.x, di, t.y * dr));
  }
  __syncthreads();
  // ---- forward radix-4 DIF stages: Q = 256,64,16,4,1 ----
  for (int Q = 256; Q >= 1; Q >>= 2) {
    for (int bf = tid; bf < 512; bf += 256) {
      const int j = bf & (Q - 1);
      const int base = ((bf & ~(Q - 1)) << 2) + j;
      const float2 x0 = z[base], x1 = z[base + Q];
      const float2 x2 = z[base + 2 * Q], x3 = z[base + 3 * Q];
      const float2 w1 = tw[2 * Q + j];
      const float2 w2 = tw[Q + j];
      const float w3r = w1.x * w2.x - w1.y * w2.y;
      const float w3i = w1.x * w2.y + w1.y * w2.x;
      const float t0r = x0.x + x2.x, t0i = x0.y + x2.y;
      const float t1r = x0.x - x2.x, t1i = x0.y - x2.y;
      const float t2r = x1.x + x3.x, t2i = x1.y + x3.y;
      const float t3r = x1.x - x3.x, t3i = x1.y - x3.y;
      z[base] = make_float2(t0r + t2r, t0i + t2i);
      const float a1r = t1r + t3i, a1i = t1i - t3r;     // (t1 - i t3)
      z[base + Q] = make_float2(a1r * w1.x - a1i * w1.y,
                                a1r * w1.y + a1i * w1.x);
      const float a2r = t0r - t2r, a2i = t0i - t2i;
      z[base + 2 * Q] = make_float2(a2r * w2.x - a2i * w2.y,
                                    a2r * w2.y + a2i * w2.x);
      const float a3r = t1r - t3i, a3i = t1i + t3r;     // (t1 + i t3)
      z[base + 3 * Q] = make_float2(a3r * w3r - a3i * w3i,
                                    a3r * w3i + a3i * w3r);
    }
    __syncthreads();
  }
  // ---- Hilbert mask in mixed-digit-reversed space ----
  for (int pp = tid; pp < TT; pp += 256) {
    if (pp != 0 && pp != 2) {
      if (pp & 2) { z[pp] = make_float2(0.f, 0.f); }
      else        { float2 v = z[pp]; z[pp] = make_float2(2.f * v.x, 2.f * v.y); }
    }
  }
  __syncthreads();
  // ---- inverse radix-4 DIT stages: Q = 1,4,16,64,256 (conj twiddles) ----
  for (int Q = 1; Q <= 256; Q <<= 2) {
    for (int bf = tid; bf < 512; bf += 256) {
      const int j = bf & (Q - 1);
      const int base = ((bf & ~(Q - 1)) << 2) + j;
      const float2 y0 = z[base], y1 = z[base + Q];
      const float2 y2 = z[base + 2 * Q], y3 = z[base + 3 * Q];
      const float2 w1 = tw[2 * Q + j];
      const float2 w2 = tw[Q + j];
      const float w3r = w1.x * w2.x - w1.y * w2.y;
      const float w3i = w1.x * w2.y + w1.y * w2.x;
      // u_m = y_m * conj(w_m)
      const float u1r = y1.x * w1.x + y1.y * w1.y;
      const float u1i = y1.y * w1.x - y1.x * w1.y;
      const float u2r = y2.x * w2.x + y2.y * w2.y;
      const float u2i = y2.y * w2.x - y2.x * w2.y;
      const float u3r = y3.x * w3r + y3.y * w3i;
      const float u3i = y3.y * w3r - y3.x * w3i;
      const float t0r = y0.x + u2r, t0i = y0.y + u2i;
      const float t1r = y0.x - u2r, t1i = y0.y - u2i;
      const float t2r = u1r + u3r, t2i = u1i + u3i;
      const float t3r = u1r - u3r, t3i = u1i - u3i;
      z[base]         = make_float2(t0r + t2r, t0i + t2i);
      z[base + Q]     = make_float2(t1r - t3i, t1i + t3r);  // t1 + i t3
      z[base + 2 * Q] = make_float2(t0r - t2r, t0i - t2i);
      z[base + 3 * Q] = make_float2(t1r + t3i, t1i - t3r);  // t1 - i t3
    }
    __syncthreads();
  }
  // ---- inverse radix-2 DIT stage (half=1024, conj twiddle) ----
  for (int bf = tid; bf < 1024; bf += 256) {
    const float2 t = tw[1024 + bf];
    const float2 u = z[bf];
    const float2 v = z[bf + 1024];
    const float vr = v.x * t.x + v.y * t.y;
    const float vi = v.y * t.x - v.x * t.y;
    z[bf] = make_float2(u.x + vr, u.y + vi);
    z[bf + 1024] = make_float2(u.x - vr, u.y - vi);
  }
  __syncthreads();
  // ---- epilogue: phase for o1, amp for o2; x1,x2 still in registers ----
  float* out1 = filt + ((size_t)n * NF + o1) * TT;
  float* out2 = filt + ((size_t)n * NF + o2) * TT;
  const float invN = 1.0f / 2048.0f;
  float phA[4], phB[4], amA[4], amB[4];
#pragma unroll
  for (int r = 0; r < 4; ++r) {
    float2 wvA = z[bA + r];
    float h1 = wvA.y * invN - acc2A[r];
    float h2 = acc1A[r] - wvA.x * invN;
    phA[r] = atan2f(h1, acc1A[r]);
    amA[r] = sqrtf(fmaf(acc2A[r], acc2A[r], h2 * h2));
    float2 wvB = z[bB + r];
    float g1 = wvB.y * invN - acc2B[r];
    float g2 = acc1B[r] - wvB.x * invN;
    phB[r] = atan2f(g1, acc1B[r]);
    amB[r] = sqrtf(fmaf(acc2B[r], acc2B[r], g2 * g2));
  }
  *(float4*)&out1[bA] = make_float4(phA[0], phA[1], phA[2], phA[3]);
  *(float4*)&out1[bB] = make_float4(phB[0], phB[1], phB[2], phB[3]);
  *(float4*)&out2[bA] = make_float4(amA[0], amA[1], amA[2], amA[3]);
  *(float4*)&out2[bB] = make_float4(amB[0], amB[1], amB[2], amB[3]);
}

// ---------------------------------------------------------------------------
// Kernel C: binned MI via MFMA (unchanged from R12 — verified 16x16x32
// layouts, 3-way exact bf16 split, counts via ones-row).
// ---------------------------------------------------------------------------
__global__ __launch_bounds__(64) void mi_kernel(const float* __restrict__ filt,
                                                float* __restrict__ mi) {
  __shared__ __align__(16) unsigned int idx32[512];  // 4 bins/dword
  __shared__ float Cs[12][19];
  const int lane = threadIdx.x;
  const int blk = blockIdx.x;           // bc*40 + jp
  const int bc = blk / 40, jp = blk % 40;
  const float* ph = filt + ((size_t)(bc * 4 + jp / 10) * NF + (jp % 10)) * TT;
  for (int g = lane; g < 512; g += 64) {
    float4 v = *(const float4*)&ph[4 * g];
    float vv[4] = {v.x, v.y, v.z, v.w};
    unsigned int packed = 0;
#pragma unroll
    for (int j = 0; j < 4; ++j) {
      int b = (int)floorf((vv[j] + 3.14159274f) / 6.2831855f * 18.0f);
      b = b < 0 ? 0 : (b > 17 ? 17 : b);
      packed |= ((unsigned int)b) << (8 * j);
    }
    idx32[g] = packed;
  }
  __syncthreads();
  const int n16 = lane & 15;    // A row m / B col n / C col
  const int quad = lane >> 4;   // k-quad (0..3)
  const int aband = n16 < 10 ? n16 : 9;
  const int ja = (jp & 3) + 4 * aband;   // scrambled amp row, same s'
  const float* aptr = filt + ((size_t)(bc * 4 + ja / 10) * NF + 10 + (ja % 10)) * TT
                      + quad * 8;
  const bool isAmp = (n16 < 10);
  const bool isOne = (n16 == 10);
  f32x4 acc0 = {0.f, 0.f, 0.f, 0.f};     // bins 0..15
  f32x4 acc1 = {0.f, 0.f, 0.f, 0.f};     // bins 16..17 (cols 16+n16)
  float4 p0 = *(const float4*)(aptr);
  float4 p1 = *(const float4*)(aptr + 4);
  for (int s = 0; s < 64; ++s) {
    float4 c0 = p0, c1 = p1;
    if (s < 63) {
      p0 = *(const float4*)(aptr + (s + 1) * 32);
      p1 = *(const float4*)(aptr + (s + 1) * 32 + 4);
    }
    float a[8] = {c0.x, c0.y, c0.z, c0.w, c1.x, c1.y, c1.z, c1.w};
    short8 ah, am_, al;
#pragma unroll
    for (int j = 0; j < 8; ++j) {
      float v = isAmp ? a[j] : (isOne ? 1.0f : 0.0f);
      unsigned int u = __float_as_uint(v);
      float h = __uint_as_float(u & 0xFFFF0000u);
      float r1 = v - h;                       // exact (<=16 sig bits)
      unsigned int u2 = __float_as_uint(r1);
      float md = __uint_as_float(u2 & 0xFFFF0000u);
      float r2 = r1 - md;                     // exact (<=8 sig bits)
      unsigned int u3 = __float_as_uint(r2);
      ah[j] = (short)(u >> 16);
      am_[j] = (short)(u2 >> 16);
      al[j] = (short)(u3 >> 16);
    }
    const int dw = s * 8 + quad * 2;
    unsigned int d0 = idx32[dw], d1 = idx32[dw + 1];
    short8 b0, b1;
#pragma unroll
    for (int j = 0; j < 8; ++j) {
      unsigned int byte = ((j < 4 ? d0 : d1) >> ((j & 3) * 8)) & 0xFFu;
      b0[j] = (byte == (unsigned int)n16) ? (short)0x3F80 : (short)0;
      b1[j] = (byte == (unsigned int)(n16 + 16)) ? (short)0x3F80 : (short)0;
    }
    acc0 = __builtin_amdgcn_mfma_f32_16x16x32_bf16(ah, b0, acc0, 0, 0, 0);
    acc0 = __builtin_amdgcn_mfma_f32_16x16x32_bf16(am_, b0, acc0, 0, 0, 0);
    acc0 = __builtin_amdgcn_mfma_f32_16x16x32_bf16(al, b0, acc0, 0, 0, 0);
    acc1 = __builtin_amdgcn_mfma_f32_16x16x32_bf16(ah, b1, acc1, 0, 0, 0);
    acc1 = __builtin_amdgcn_mfma_f32_16x16x32_bf16(am_, b1, acc1, 0, 0, 0);
    acc1 = __builtin_amdgcn_mfma_f32_16x16x32_bf16(al, b1, acc1, 0, 0, 0);
  }
#pragma unroll
  for (int r = 0; r < 4; ++r) {
    int row = quad * 4 + r;
    if (row < 11) {
      Cs[row][n16] = acc0[r];
      if (n16 < 2) Cs[row][16 + n16] = acc1[r];
    }
  }
  __syncthreads();
  if (lane < 10) {
    float tot = 0.f, mb_[18];
#pragma unroll
    for (int b = 0; b < 18; ++b) {
      float mb = Cs[lane][b] / fmaxf(Cs[10][b], 1.0f);
      mb_[b] = mb; tot += mb;
    }
    tot = fmaxf(tot, 1e-12f);
    float s = 0.f;
#pragma unroll
    for (int b = 0; b < 18; ++b) {
      float pb = mb_[b] / tot;
      s += pb * logf(fmaxf(pb, 1e-12f));
    }
    const float LOGN = 2.8903717578961645f; // log(18)
    mi[(size_t)blk * 10 + lane] = (LOGN + s) / LOGN;
  }
}

// ---------------------------------------------------------------------------
// Kernel D: mean over the scrambled s' axis -> out (4,8,10,10)
// ---------------------------------------------------------------------------
__global__ void out_kernel(const float* __restrict__ mi, float* __restrict__ out) {
  int i = blockIdx.x * 256 + threadIdx.x;
  if (i < 3200) {
    int a = i % 10, p = (i / 10) % 10, bc = i / 100;
    float s = 0.f;
    for (int sp = 0; sp < 4; ++sp)
      s += mi[((size_t)(bc * 40 + p * 4 + sp)) * 10 + a];
    out[i] = 0.25f * s;
  }
}

extern "C" void kernel_launch(void* const* d_in, const int* in_sizes, int n_in,
                              void* d_out, int out_size, void* d_ws, size_t ws_size,
                              hipStream_t stream) {
  (void)in_sizes; (void)n_in; (void)out_size; (void)ws_size;
  const float* x = (const float*)d_in[0];     // (4,8,4,2048) fp32
  const float* ker = (const float*)d_in[1];   // (20,769) fp32
  float* out = (float*)d_out;                 // 3200 fp32
  float* filt = (float*)d_ws;                 // 128*20*2048 fp32 (~21 MB)
  float* mi = filt + (size_t)NS * NF * TT;    // 12800 fp32
  float2* tw = (float2*)(mi + 12800);         // 2048 float2 (16 KB)

  tw_kernel<<<(TT + 255) / 256, 256, 0, stream>>>(tw);
  convhil_kernel<<<NS * 10, 256, 0, stream>>>(x, ker, tw, filt);
  mi_kernel<<<32 * 40, 64, 0, stream>>>(filt, mi);
  out_kernel<<<(3200 + 255) / 256, 256, 0, stream>>>(mi, out);
}

// Round 16
// 139.375 us; speedup vs baseline: 1.0932x; 1.0932x over previous
//
#include <hip/hip_runtime.h>
#include <math.h>

#define TT 2048
#define LK 769
#define NF 20
#define NS 128
#define NB 18

typedef __attribute__((ext_vector_type(8))) short short8;
typedef __attribute__((ext_vector_type(4))) float f32x4;

// ---------------------------------------------------------------------------
// Kernel P: one-time prep. Blocks 0..7: twiddle table tw[half+j] =
// exp(-i*pi*j/half) (same formula as before -> bit-identical). Blocks 8..27:
// symmetrized filter o = blk-8 into hsym[o][784] + 8-aligned nonzero range
// into rng[2o],rng[2o+1]. Hoisted out of convhil (was recomputed x1280).
// ---------------------------------------------------------------------------
__global__ __launch_bounds__(256) void prep_kernel(const float* __restrict__ ker,
                                                   float2* __restrict__ tw,
                                                   float* __restrict__ hsym,
                                                   int* __restrict__ rng) {
  __shared__ int red[4][2];
  const int blk = blockIdx.x;
  const int tid = threadIdx.x;
  if (blk < 8) {
    int i = blk * 256 + tid;
    if (i == 0) { tw[0] = make_float2(1.f, 0.f); }
    else {
      int half = 1 << (31 - __clz(i));
      int j = i - half;
      float ang = -3.14159265358979323846f * (float)j / (float)half;
      float s, c;
      sincosf(ang, &s, &c);
      tw[i] = make_float2(c, s);
    }
    return;
  }
  const int o = blk - 8;
  const float* kr = ker + o * LK;
  int k0 = 784, k1 = 0;
  for (int k = tid; k < 784; k += 256) {
    float v = 0.f;
    if (k < LK) v = 0.5f * (kr[k] + kr[LK - 1 - k]);
    hsym[o * 784 + k] = v;
    if (v != 0.f) { k0 = min(k0, k); k1 = max(k1, k + 1); }
  }
#pragma unroll
  for (int off = 32; off > 0; off >>= 1) {
    k0 = min(k0, __shfl_down(k0, off));
    k1 = max(k1, __shfl_down(k1, off));
  }
  if ((tid & 63) == 0) { red[tid >> 6][0] = k0; red[tid >> 6][1] = k1; }
  __syncthreads();
  if (tid == 0) {
    k0 = min(min(red[0][0], red[1][0]), min(red[2][0], red[3][0]));
    k1 = max(max(red[0][1], red[1][1]), max(red[2][1], red[3][1]));
    rng[2 * o] = k0 & ~7;              // 8-aligned (extra taps exact zeros)
    rng[2 * o + 1] = (k1 + 7) & ~7;
  }
}

// ---------------------------------------------------------------------------
// Kernel A: FUSED conv + Hilbert (R14/R15 structure). R16: filters+ranges
// precomputed (prep_kernel) -> no per-block symmetrize/scan/reduce.
// Twiddles from global (L1-resident). Occupancy is grid-limited (1280
// blocks = 5/CU), so LDS is already non-binding.
// ---------------------------------------------------------------------------
__global__ __launch_bounds__(256) void convhil_kernel(const float* __restrict__ x,
                                                      const float* __restrict__ hsym,
                                                      const int* __restrict__ rng,
                                                      const float2* __restrict__ tw,
                                                      float* __restrict__ filt) {
  __shared__ __align__(16) float smem[4400];   // w[2832]+hs1[784]+hs2[784]; z overlays
  float* w   = smem;
  float* hs1 = smem + 2832;
  float* hs2 = smem + 3616;
  float2* z  = (float2*)smem;                  // 2048 float2 = 4096 floats < 4400
  const int tid = threadIdx.x;
  const int ord = blockIdx.x;
  const int p = ord / NS;                   // 0..9, longest pair first
  const int n = ord % NS;
  const int o1 = p;                          // pha band
  const int o2 = 10 + (9 - p);               // amp band (short with long)
  const float* xr = x + n * TT;
  for (int j = tid; j < 2832; j += 256) {
    float v = 0.f;
    if (j < 2816) {
      int m = j - 384;              // spad[j+384] -> original index (j+384)-768
      if (m < 0) m = -m;            // reflect (edge excluded)
      if (m > 2047) m = 4094 - m;
      v = xr[m];
    }
    w[j] = v;
  }
  const float* h1g = hsym + o1 * 784;
  const float* h2g = hsym + o2 * 784;
  for (int k = tid; k < 784; k += 256) {
    hs1[k] = h1g[k];
    hs2[k] = h2g[k];
  }
  const int A0 = rng[2 * o1], A1 = rng[2 * o1 + 1];   // uniform -> scalar loads
  const int B0 = rng[2 * o2], B1 = rng[2 * o2 + 1];
  const int U0 = min(A0, B0);
  const int U1 = max(A1, B1);
  __syncthreads();

  const int bA = 4 * tid;           // group A outputs [bA, bA+4)
  const int bB = 1024 + 4 * tid;    // group B outputs [bB, bB+4)
  float acc1A[4], acc1B[4], acc2A[4], acc2B[4];
#pragma unroll
  for (int r = 0; r < 4; ++r) { acc1A[r] = 0.f; acc1B[r] = 0.f; acc2A[r] = 0.f; acc2B[r] = 0.f; }
  if (U0 < U1) {
    // rolling window: a0..a2 cover w[bA+k .. bA+k+12)
    float4 a0 = *(const float4*)&w[bA + U0];
    float4 a1 = *(const float4*)&w[bA + U0 + 4];
    float4 a2 = *(const float4*)&w[bA + U0 + 8];
    float4 b0 = *(const float4*)&w[bB + U0];
    float4 b1 = *(const float4*)&w[bB + U0 + 4];
    float4 b2 = *(const float4*)&w[bB + U0 + 8];
    float4 h1a = *(const float4*)&hs1[U0];
    float4 h1b = *(const float4*)&hs1[U0 + 4];
    float4 h2a = *(const float4*)&hs2[U0];
    float4 h2b = *(const float4*)&hs2[U0 + 4];
    for (int k = U0; k < U1; k += 8) {
      float4 a3 = *(const float4*)&w[bA + k + 12];
      float4 a4 = *(const float4*)&w[bA + k + 16];
      float4 b3 = *(const float4*)&w[bB + k + 12];
      float4 b4 = *(const float4*)&w[bB + k + 16];
      float4 h1an = *(const float4*)&hs1[k + 8];
      float4 h1bn = *(const float4*)&hs1[k + 12];
      float4 h2an = *(const float4*)&hs2[k + 8];
      float4 h2bn = *(const float4*)&hs2[k + 12];
      float wa[11] = {a0.x, a0.y, a0.z, a0.w, a1.x, a1.y, a1.z, a1.w,
                      a2.x, a2.y, a2.z};
      float wb[11] = {b0.x, b0.y, b0.z, b0.w, b1.x, b1.y, b1.z, b1.w,
                      b2.x, b2.y, b2.z};
      float h1[8] = {h1a.x, h1a.y, h1a.z, h1a.w, h1b.x, h1b.y, h1b.z, h1b.w};
      float h2[8] = {h2a.x, h2a.y, h2a.z, h2a.w, h2b.x, h2b.y, h2b.z, h2b.w};
      if (k >= A0 && k < A1) {
#pragma unroll
        for (int r = 0; r < 4; ++r) {
#pragma unroll
          for (int j = 0; j < 8; ++j) {
            acc1A[r] = fmaf(h1[j], wa[r + j], acc1A[r]);
            acc1B[r] = fmaf(h1[j], wb[r + j], acc1B[r]);
          }
        }
      }
      if (k >= B0 && k < B1) {
#pragma unroll
        for (int r = 0; r < 4; ++r) {
#pragma unroll
          for (int j = 0; j < 8; ++j) {
            acc2A[r] = fmaf(h2[j], wa[r + j], acc2A[r]);
            acc2B[r] = fmaf(h2[j], wb[r + j], acc2B[r]);
          }
        }
      }
      a0 = a2; a1 = a3; a2 = a4;
      b0 = b2; b1 = b3; b2 = b4;
      h1a = h1an; h1b = h1bn;
      h2a = h2an; h2b = h2bn;
    }
  }
  // ---- hand off to FFT: z = out1 + i*out2 (overlays dead w/hs region) ----
  __syncthreads();                    // everyone done reading w/hs
#pragma unroll
  for (int r = 0; r < 4; ++r) {
    z[bA + r] = make_float2(acc1A[r], acc2A[r]);
    z[bB + r] = make_float2(acc1B[r], acc2B[r]);
  }
  __syncthreads();
  // ---- forward radix-2 DIF stage (half=1024) ----
  for (int bf = tid; bf < 1024; bf += 256) {
    const float2 t = tw[1024 + bf];
    const float2 u = z[bf];
    const float2 v = z[bf + 1024];
    z[bf] = make_float2(u.x + v.x, u.y + v.y);
    const float dr = u.x - v.x, di = u.y - v.y;
    z[bf + 1024] = make_float2(fmaf(t.x, dr, -(t.y * di)),
                               fmaf(t.x, di, t.y * dr));
  }
  __syncthreads();
  // ---- forward radix-4 DIF stages: Q = 256,64,16,4,1 ----
  for (int Q = 256; Q >= 1; Q >>= 2) {
    for (int bf = tid; bf < 512; bf += 256) {
      const int j = bf & (Q - 1);
      const int base = ((bf & ~(Q - 1)) << 2) + j;
      const float2 x0 = z[base], x1 = z[base + Q];
      const float2 x2 = z[base + 2 * Q], x3 = z[base + 3 * Q];
      const float2 w1 = tw[2 * Q + j];
      const float2 w2 = tw[Q + j];
      const float w3r = w1.x * w2.x - w1.y * w2.y;
      const float w3i = w1.x * w2.y + w1.y * w2.x;
      const float t0r = x0.x + x2.x, t0i = x0.y + x2.y;
      const float t1r = x0.x - x2.x, t1i = x0.y - x2.y;
      const float t2r = x1.x + x3.x, t2i = x1.y + x3.y;
      const float t3r = x1.x - x3.x, t3i = x1.y - x3.y;
      z[base] = make_float2(t0r + t2r, t0i + t2i);
      const float a1r = t1r + t3i, a1i = t1i - t3r;     // (t1 - i t3)
      z[base + Q] = make_float2(a1r * w1.x - a1i * w1.y,
                                a1r * w1.y + a1i * w1.x);
      const float a2r = t0r - t2r, a2i = t0i - t2i;
      z[base + 2 * Q] = make_float2(a2r * w2.x - a2i * w2.y,
                                    a2r * w2.y + a2i * w2.x);
      const float a3r = t1r - t3i, a3i = t1i + t3r;     // (t1 + i t3)
      z[base + 3 * Q] = make_float2(a3r * w3r - a3i * w3i,
                                    a3r * w3i + a3i * w3r);
    }
    __syncthreads();
  }
  // ---- Hilbert mask in mixed-digit-reversed space ----
  for (int pp = tid; pp < TT; pp += 256) {
    if (pp != 0 && pp != 2) {
      if (pp & 2) { z[pp] = make_float2(0.f, 0.f); }
      else        { float2 v = z[pp]; z[pp] = make_float2(2.f * v.x, 2.f * v.y); }
    }
  }
  __syncthreads();
  // ---- inverse radix-4 DIT stages: Q = 1,4,16,64,256 (conj twiddles) ----
  for (int Q = 1; Q <= 256; Q <<= 2) {
    for (int bf = tid; bf < 512; bf += 256) {
      const int j = bf & (Q - 1);
      const int base = ((bf & ~(Q - 1)) << 2) + j;
      const float2 y0 = z[base], y1 = z[base + Q];
      const float2 y2 = z[base + 2 * Q], y3 = z[base + 3 * Q];
      const float2 w1 = tw[2 * Q + j];
      const float2 w2 = tw[Q + j];
      const float w3r = w1.x * w2.x - w1.y * w2.y;
      const float w3i = w1.x * w2.y + w1.y * w2.x;
      // u_m = y_m * conj(w_m)
      const float u1r = y1.x * w1.x + y1.y * w1.y;
      const float u1i = y1.y * w1.x - y1.x * w1.y;
      const float u2r = y2.x * w2.x + y2.y * w2.y;
      const float u2i = y2.y * w2.x - y2.x * w2.y;
      const float u3r = y3.x * w3r + y3.y * w3i;
      const float u3i = y3.y * w3r - y3.x * w3i;
      const float t0r = y0.x + u2r, t0i = y0.y + u2i;
      const float t1r = y0.x - u2r, t1i = y0.y - u2i;
      const float t2r = u1r + u3r, t2i = u1i + u3i;
      const float t3r = u1r - u3r, t3i = u1i - u3i;
      z[base]         = make_float2(t0r + t2r, t0i + t2i);
      z[base + Q]     = make_float2(t1r - t3i, t1i + t3r);  // t1 + i t3
      z[base + 2 * Q] = make_float2(t0r - t2r, t0i - t2i);
      z[base + 3 * Q] = make_float2(t1r + t3i, t1i - t3r);  // t1 - i t3
    }
    __syncthreads();
  }
  // ---- inverse radix-2 DIT stage (half=1024, conj twiddle) ----
  for (int bf = tid; bf < 1024; bf += 256) {
    const float2 t = tw[1024 + bf];
    const float2 u = z[bf];
    const float2 v = z[bf + 1024];
    const float vr = v.x * t.x + v.y * t.y;
    const float vi = v.y * t.x - v.x * t.y;
    z[bf] = make_float2(u.x + vr, u.y + vi);
    z[bf + 1024] = make_float2(u.x - vr, u.y - vi);
  }
  __syncthreads();
  // ---- epilogue: phase for o1, amp for o2; x1,x2 still in registers ----
  float* out1 = filt + ((size_t)n * NF + o1) * TT;
  float* out2 = filt + ((size_t)n * NF + o2) * TT;
  const float invN = 1.0f / 2048.0f;
  float phA[4], phB[4], amA[4], amB[4];
#pragma unroll
  for (int r = 0; r < 4; ++r) {
    float2 wvA = z[bA + r];
    float h1 = wvA.y * invN - acc2A[r];
    float h2 = acc1A[r] - wvA.x * invN;
    phA[r] = atan2f(h1, acc1A[r]);
    amA[r] = sqrtf(fmaf(acc2A[r], acc2A[r], h2 * h2));
    float2 wvB = z[bB + r];
    float g1 = wvB.y * invN - acc2B[r];
    float g2 = acc1B[r] - wvB.x * invN;
    phB[r] = atan2f(g1, acc1B[r]);
    amB[r] = sqrtf(fmaf(acc2B[r], acc2B[r], g2 * g2));
  }
  *(float4*)&out1[bA] = make_float4(phA[0], phA[1], phA[2], phA[3]);
  *(float4*)&out1[bB] = make_float4(phB[0], phB[1], phB[2], phB[3]);
  *(float4*)&out2[bA] = make_float4(amA[0], amA[1], amA[2], amA[3]);
  *(float4*)&out2[bB] = make_float4(amB[0], amB[1], amB[2], amB[3]);
}

// ---------------------------------------------------------------------------
// Kernel C: binned MI via MFMA, R16: 256 threads = 4 waves per block with
// K-split (wave w does steps [16w,16w+16)), partial C tiles reduced via LDS.
// R12-R15 used 1 wave/block -> only ~5 waves/CU; the 3-dependent-MFMA chain
// and ~200 VALU cyc/step ran nearly unhidden. Verified 16x16x32 layouts.
// ---------------------------------------------------------------------------
__global__ __launch_bounds__(256) void mi_kernel(const float* __restrict__ filt,
                                                 float* __restrict__ mi) {
  __shared__ __align__(16) unsigned int idx32[512];  // 4 bins/dword
  __shared__ float Cp[4][12][19];                    // per-wave partial C
  const int tid = threadIdx.x;
  const int wave = tid >> 6;
  const int lane = tid & 63;
  const int blk = blockIdx.x;           // bc*40 + jp
  const int bc = blk / 40, jp = blk % 40;
  const float* ph = filt + ((size_t)(bc * 4 + jp / 10) * NF + (jp % 10)) * TT;
  for (int g = tid; g < 512; g += 256) {
    float4 v = *(const float4*)&ph[4 * g];
    float vv[4] = {v.x, v.y, v.z, v.w};
    unsigned int packed = 0;
#pragma unroll
    for (int j = 0; j < 4; ++j) {
      int b = (int)floorf((vv[j] + 3.14159274f) / 6.2831855f * 18.0f);
      b = b < 0 ? 0 : (b > 17 ? 17 : b);
      packed |= ((unsigned int)b) << (8 * j);
    }
    idx32[g] = packed;
  }
  __syncthreads();
  const int n16 = lane & 15;    // A row m / B col n / C col
  const int quad = lane >> 4;   // k-quad (0..3)
  const int aband = n16 < 10 ? n16 : 9;
  const int ja = (jp & 3) + 4 * aband;   // scrambled amp row, same s'
  const float* aptr = filt + ((size_t)(bc * 4 + ja / 10) * NF + 10 + (ja % 10)) * TT
                      + quad * 8;
  const bool isAmp = (n16 < 10);
  const bool isOne = (n16 == 10);
  f32x4 acc0 = {0.f, 0.f, 0.f, 0.f};     // bins 0..15
  f32x4 acc1 = {0.f, 0.f, 0.f, 0.f};     // bins 16..17 (cols 16+n16)
  const int s0 = wave * 16, s1 = s0 + 16;
  float4 p0 = *(const float4*)(aptr + s0 * 32);
  float4 p1 = *(const float4*)(aptr + s0 * 32 + 4);
  for (int s = s0; s < s1; ++s) {
    float4 c0 = p0, c1 = p1;
    if (s < s1 - 1) {
      p0 = *(const float4*)(aptr + (s + 1) * 32);
      p1 = *(const float4*)(aptr + (s + 1) * 32 + 4);
    }
    float a[8] = {c0.x, c0.y, c0.z, c0.w, c1.x, c1.y, c1.z, c1.w};
    short8 ah, am_, al;
#pragma unroll
    for (int j = 0; j < 8; ++j) {
      float v = isAmp ? a[j] : (isOne ? 1.0f : 0.0f);
      unsigned int u = __float_as_uint(v);
      float h = __uint_as_float(u & 0xFFFF0000u);
      float r1 = v - h;                       // exact (<=16 sig bits)
      unsigned int u2 = __float_as_uint(r1);
      float md = __uint_as_float(u2 & 0xFFFF0000u);
      float r2 = r1 - md;                     // exact (<=8 sig bits)
      unsigned int u3 = __float_as_uint(r2);
      ah[j] = (short)(u >> 16);
      am_[j] = (short)(u2 >> 16);
      al[j] = (short)(u3 >> 16);
    }
    const int dw = s * 8 + quad * 2;
    unsigned int d0 = idx32[dw], d1 = idx32[dw + 1];
    short8 b0, b1;
#pragma unroll
    for (int j = 0; j < 8; ++j) {
      unsigned int byte = ((j < 4 ? d0 : d1) >> ((j & 3) * 8)) & 0xFFu;
      b0[j] = (byte == (unsigned int)n16) ? (short)0x3F80 : (short)0;
      b1[j] = (byte == (unsigned int)(n16 + 16)) ? (short)0x3F80 : (short)0;
    }
    acc0 = __builtin_amdgcn_mfma_f32_16x16x32_bf16(ah, b0, acc0, 0, 0, 0);
    acc0 = __builtin_amdgcn_mfma_f32_16x16x32_bf16(am_, b0, acc0, 0, 0, 0);
    acc0 = __builtin_amdgcn_mfma_f32_16x16x32_bf16(al, b0, acc0, 0, 0, 0);
    acc1 = __builtin_amdgcn_mfma_f32_16x16x32_bf16(ah, b1, acc1, 0, 0, 0);
    acc1 = __builtin_amdgcn_mfma_f32_16x16x32_bf16(am_, b1, acc1, 0, 0, 0);
    acc1 = __builtin_amdgcn_mfma_f32_16x16x32_bf16(al, b1, acc1, 0, 0, 0);
  }
#pragma unroll
  for (int r = 0; r < 4; ++r) {
    int row = quad * 4 + r;
    if (row < 11) {
      Cp[wave][row][n16] = acc0[r];
      if (n16 < 2) Cp[wave][row][16 + n16] = acc1[r];
    }
  }
  __syncthreads();
  if (tid < 10) {
    float tot = 0.f, mb_[18];
#pragma unroll
    for (int b = 0; b < 18; ++b) {
      float s = Cp[0][tid][b] + Cp[1][tid][b] + Cp[2][tid][b] + Cp[3][tid][b];
      float c = Cp[0][10][b] + Cp[1][10][b] + Cp[2][10][b] + Cp[3][10][b];
      float mb = s / fmaxf(c, 1.0f);
      mb_[b] = mb; tot += mb;
    }
    tot = fmaxf(tot, 1e-12f);
    float s = 0.f;
#pragma unroll
    for (int b = 0; b < 18; ++b) {
      float pb = mb_[b] / tot;
      s += pb * logf(fmaxf(pb, 1e-12f));
    }
    const float LOGN = 2.8903717578961645f; // log(18)
    mi[(size_t)blk * 10 + tid] = (LOGN + s) / LOGN;
  }
}

// ---------------------------------------------------------------------------
// Kernel D: mean over the scrambled s' axis -> out (4,8,10,10)
// ---------------------------------------------------------------------------
__global__ void out_kernel(const float* __restrict__ mi, float* __restrict__ out) {
  int i = blockIdx.x * 256 + threadIdx.x;
  if (i < 3200) {
    int a = i % 10, p = (i / 10) % 10, bc = i / 100;
    float s = 0.f;
    for (int sp = 0; sp < 4; ++sp)
      s += mi[((size_t)(bc * 40 + p * 4 + sp)) * 10 + a];
    out[i] = 0.25f * s;
  }
}

extern "C" void kernel_launch(void* const* d_in, const int* in_sizes, int n_in,
                              void* d_out, int out_size, void* d_ws, size_t ws_size,
                              hipStream_t stream) {
  (void)in_sizes; (void)n_in; (void)out_size; (void)ws_size;
  const float* x = (const float*)d_in[0];     // (4,8,4,2048) fp32
  const float* ker = (const float*)d_in[1];   // (20,769) fp32
  float* out = (float*)d_out;                 // 3200 fp32
  float* filt = (float*)d_ws;                 // 128*20*2048 fp32 (~21 MB)
  float* mi = filt + (size_t)NS * NF * TT;    // 12800 fp32
  float2* tw = (float2*)(mi + 12800);         // 2048 float2 (16 KB)
  float* hsym = (float*)(tw + TT);            // 20*784 fp32
  int* rng = (int*)(hsym + NF * 784);         // 40 ints

  prep_kernel<<<28, 256, 0, stream>>>(ker, tw, hsym, rng);
  convhil_kernel<<<NS * 10, 256, 0, stream>>>(x, hsym, rng, tw, filt);
  mi_kernel<<<32 * 40, 256, 0, stream>>>(filt, mi);
  out_kernel<<<(3200 + 255) / 256, 256, 0, stream>>>(mi, out);
}